// Round 1
// baseline (1099.971 us; speedup 1.0000x reference)
//
#include <hip/hip_runtime.h>

#define NB    8
#define NCIN  256
#define NH    128
#define NW    128
#define NHW   16384      // NH*NW
#define NQKV  192        // 3*T
#define NCOUT 256

// ---------------------------------------------------------------------------
// K1: qkv[b][m][n] = sum_k Wq[m][k] * x[b][k][n]   (1x1 conv as panel GEMM)
// Weights via wave-uniform global indices -> scalar loads (s_load_dwordx4).
// ---------------------------------------------------------------------------
__global__ __launch_bounds__(256, 2) void k1_qkv(
    const float* __restrict__ x, const float* __restrict__ Wq,
    float* __restrict__ qkv)
{
  const int tid = threadIdx.x;
  const int P0  = blockIdx.x * 256;
  const int b   = P0 >> 14;            // /NHW
  const int n0  = P0 & (NHW - 1);
  const int m0  = blockIdx.y * 96;

  const float* xp = x + (size_t)b * NCIN * NHW + n0 + tid;

  float acc[96];
#pragma unroll
  for (int m = 0; m < 96; m++) acc[m] = 0.f;

  float cur[4], nxt[4] = {0.f, 0.f, 0.f, 0.f};
#pragma unroll
  for (int j = 0; j < 4; j++) cur[j] = xp[(size_t)j * NHW];

  for (int k = 0; k < 256; k += 4) {
    if (k + 4 < 256) {
#pragma unroll
      for (int j = 0; j < 4; j++) nxt[j] = xp[(size_t)(k + 4 + j) * NHW];
    }
    const float* wr = Wq + (size_t)m0 * 256 + k;
#pragma unroll
    for (int m = 0; m < 96; m++) {
      acc[m] = fmaf(cur[0], wr[m * 256 + 0], acc[m]);
      acc[m] = fmaf(cur[1], wr[m * 256 + 1], acc[m]);
      acc[m] = fmaf(cur[2], wr[m * 256 + 2], acc[m]);
      acc[m] = fmaf(cur[3], wr[m * 256 + 3], acc[m]);
    }
#pragma unroll
    for (int j = 0; j < 4; j++) cur[j] = nxt[j];
  }

  float* op = qkv + (size_t)b * NQKV * NHW + (size_t)m0 * NHW + n0 + tid;
#pragma unroll
  for (int m = 0; m < 96; m++) op[(size_t)m * NHW] = acc[m];
}

// ---------------------------------------------------------------------------
// K2q: kv partial sums for attention groups 0..7 (sourced from qkv).
// kv[b][g][d][e] += sum_n relu(k)[d] * {v[e], 1}
// ---------------------------------------------------------------------------
__global__ __launch_bounds__(256, 4) void k2_qkv_kv(
    const float* __restrict__ qkv, float* __restrict__ kvb)
{
  __shared__ float red[4 * 72];
  const int tid = threadIdx.x;
  const int gg  = blockIdx.y;               // 0..7
  const int P0  = blockIdx.x * 2048;
  const int b   = P0 >> 14;
  const int n0  = P0 & (NHW - 1);

  const float* base = qkv + ((size_t)b * NQKV + gg * 24) * NHW + n0 + tid;

  float acc[72];
#pragma unroll
  for (int i = 0; i < 72; i++) acc[i] = 0.f;

  for (int it = 0; it < 8; it++) {
    const int off = it * 256;
    float kk[8], vv[8];
#pragma unroll
    for (int j = 0; j < 8; j++) kk[j] = fmaxf(base[(size_t)(8 + j) * NHW + off], 0.f);
#pragma unroll
    for (int j = 0; j < 8; j++) vv[j] = base[(size_t)(16 + j) * NHW + off];
#pragma unroll
    for (int d = 0; d < 8; d++) {
#pragma unroll
      for (int e = 0; e < 8; e++) acc[d * 9 + e] = fmaf(kk[d], vv[e], acc[d * 9 + e]);
      acc[d * 9 + 8] += kk[d];
    }
  }

  const int wave = tid >> 6, lane = tid & 63;
#pragma unroll
  for (int i = 0; i < 72; i++) {
    float v = acc[i];
    v += __shfl_down(v, 32);
    v += __shfl_down(v, 16);
    v += __shfl_down(v, 8);
    v += __shfl_down(v, 4);
    v += __shfl_down(v, 2);
    v += __shfl_down(v, 1);
    if (lane == 0) red[wave * 72 + i] = v;
  }
  __syncthreads();
  if (tid < 72) {
    float s = red[tid] + red[72 + tid] + red[144 + tid] + red[216 + tid];
    atomicAdd(&kvb[((size_t)b * 16 + gg) * 72 + tid], s);
  }
}

// ---------------------------------------------------------------------------
// K2d: for attention groups 8..15 (sourced from depthwise conv d):
//  - stage qkv halo (24 ch) in LDS, apply W_p in place -> p
//  - depthwise 3x3 -> d; write relu'd q-channels to dq; accumulate kv partials
// tile = 32 wide x 16 tall, halo 34x18
// ---------------------------------------------------------------------------
#define HALO_W 34
#define HALO_H 18
#define NPOS   (HALO_W * HALO_H)   // 612

__global__ __launch_bounds__(256, 2) void k2_dw(
    const float* __restrict__ qkv, const float* __restrict__ Wp,
    const float* __restrict__ Wd, float* __restrict__ dq,
    float* __restrict__ kvb)
{
  __shared__ float pbuf[24 * NPOS];
  __shared__ float red[4 * 72];

  const int tid  = threadIdx.x;
  const int gg8  = blockIdx.y;            // 0..7  (attention group = 8+gg8)
  const int bt   = blockIdx.x;            // b*32 + tile
  const int b    = bt >> 5;
  const int tile = bt & 31;
  const int ty0  = (tile >> 2) * 16;      // 8 tiles in y
  const int tx0  = (tile & 3) * 32;       // 4 tiles in x

  const float* src = qkv + ((size_t)b * NQKV + gg8 * 24) * NHW;

  // phase 1: load qkv halo into LDS (zero-padded)
  for (int idx = tid; idx < 24 * NPOS; idx += 256) {
    const int c = idx / NPOS, pos = idx % NPOS;
    const int hy = pos / HALO_W, hx = pos % HALO_W;
    const int y = ty0 + hy - 1, xx = tx0 + hx - 1;
    float v = 0.f;
    if (y >= 0 && y < NH && xx >= 0 && xx < NW) v = src[(size_t)c * NHW + y * NW + xx];
    pbuf[idx] = v;
  }
  __syncthreads();

  // phase 1b: apply W_p in place (each task owns its 8 LDS slots)
  for (int t = tid; t < 3 * NPOS; t += 256) {
    const int gloc = t / NPOS, pos = t % NPOS;
    float qv[8];
#pragma unroll
    for (int i = 0; i < 8; i++) qv[i] = pbuf[(gloc * 8 + i) * NPOS + pos];
    const float* wp = Wp + (size_t)(gg8 * 3 + gloc) * 64;
#pragma unroll
    for (int o = 0; o < 8; o++) {
      float s = 0.f;
#pragma unroll
      for (int i = 0; i < 8; i++) s = fmaf(wp[o * 8 + i], qv[i], s);
      pbuf[(gloc * 8 + o) * NPOS + pos] = s;
    }
  }
  __syncthreads();

  // phase 2: depthwise 3x3 + outputs
  float acc[72];
#pragma unroll
  for (int i = 0; i < 72; i++) acc[i] = 0.f;

  const float* wdb = Wd + (size_t)gg8 * 24 * 9;

  for (int pp = tid; pp < 512; pp += 256) {
    const int ty = pp >> 5, tx = pp & 31;
    const int n  = (ty0 + ty) * NW + (tx0 + tx);
    float kk[8], vv[8];
#pragma unroll
    for (int cc = 0; cc < 24; cc++) {
      const float* pb = pbuf + cc * NPOS + ty * HALO_W + tx;
      const float* w  = wdb + cc * 9;
      float s = 0.f;
      s = fmaf(w[0], pb[0], s);
      s = fmaf(w[1], pb[1], s);
      s = fmaf(w[2], pb[2], s);
      s = fmaf(w[3], pb[HALO_W + 0], s);
      s = fmaf(w[4], pb[HALO_W + 1], s);
      s = fmaf(w[5], pb[HALO_W + 2], s);
      s = fmaf(w[6], pb[2 * HALO_W + 0], s);
      s = fmaf(w[7], pb[2 * HALO_W + 1], s);
      s = fmaf(w[8], pb[2 * HALO_W + 2], s);
      if (cc < 8) {
        dq[((size_t)b * 64 + gg8 * 8 + cc) * NHW + n] = fmaxf(s, 0.f);
      } else if (cc < 16) {
        kk[cc - 8] = fmaxf(s, 0.f);
      } else {
        vv[cc - 16] = s;
      }
    }
#pragma unroll
    for (int d = 0; d < 8; d++) {
#pragma unroll
      for (int e = 0; e < 8; e++) acc[d * 9 + e] = fmaf(kk[d], vv[e], acc[d * 9 + e]);
      acc[d * 9 + 8] += kk[d];
    }
  }

  const int wave = tid >> 6, lane = tid & 63;
#pragma unroll
  for (int i = 0; i < 72; i++) {
    float v = acc[i];
    v += __shfl_down(v, 32);
    v += __shfl_down(v, 16);
    v += __shfl_down(v, 8);
    v += __shfl_down(v, 4);
    v += __shfl_down(v, 2);
    v += __shfl_down(v, 1);
    if (lane == 0) red[wave * 72 + i] = v;
  }
  __syncthreads();
  if (tid < 72) {
    float s = red[tid] + red[72 + tid] + red[144 + tid] + red[216 + tid];
    atomicAdd(&kvb[((size_t)b * 16 + (8 + gg8)) * 72 + tid], s);
  }
}

// ---------------------------------------------------------------------------
// K3: per pixel: q (16 groups x 8) -> o = (q . kv)[:8] / (q . kv)[8]
//     then y = Wffn @ o, BN affine.  Wffn/kv/bn via uniform scalar loads.
// ---------------------------------------------------------------------------
__global__ __launch_bounds__(256, 2) void k3_attn_ffn(
    const float* __restrict__ qkv, const float* __restrict__ dq,
    const float* __restrict__ kvb, const float* __restrict__ Wf,
    const float* __restrict__ gamma, const float* __restrict__ beta,
    const float* __restrict__ mean, const float* __restrict__ var,
    float* __restrict__ out)
{
  const int tid = threadIdx.x;
  const int P0  = blockIdx.x * 256;
  const int b   = P0 >> 14;
  const int n0  = P0 & (NHW - 1);
  const int m0  = blockIdx.y * 128;
  const int n   = n0 + tid;

  float acc[128];
#pragma unroll
  for (int m = 0; m < 128; m++) acc[m] = 0.f;

  const float* kvB = kvb + (size_t)b * 16 * 72;

  // prefetch q for group 0
  float q[8], qn[8];
  {
    const float* qp = qkv + ((size_t)b * NQKV + 0) * NHW + n;
#pragma unroll
    for (int j = 0; j < 8; j++) q[j] = qp[(size_t)j * NHW];
  }

  for (int g = 0; g < 16; g++) {
    // prefetch next group's q (raw)
    if (g < 15) {
      const int gn = g + 1;
      const float* qp = (gn < 8)
          ? qkv + ((size_t)b * NQKV + gn * 24) * NHW + n
          : dq + ((size_t)b * 64 + (gn - 8) * 8) * NHW + n;
#pragma unroll
      for (int j = 0; j < 8; j++) qn[j] = qp[(size_t)j * NHW];
    }

    float qv[8];
#pragma unroll
    for (int j = 0; j < 8; j++) qv[j] = (g < 8) ? fmaxf(q[j], 0.f) : q[j];

    const float* kvg = kvB + g * 72;
    float num[9];
#pragma unroll
    for (int e = 0; e < 9; e++) {
      float s = 0.f;
#pragma unroll
      for (int d = 0; d < 8; d++) s = fmaf(qv[d], kvg[d * 9 + e], s);
      num[e] = s;
    }
    const float r = __builtin_amdgcn_rcpf(num[8] + 1e-15f);
    float o8[8];
#pragma unroll
    for (int e = 0; e < 8; e++) o8[e] = num[e] * r;

    const float* wg = Wf + (size_t)m0 * 128 + g * 8;
#pragma unroll
    for (int m = 0; m < 128; m++) {
#pragma unroll
      for (int e = 0; e < 8; e++) acc[m] = fmaf(o8[e], wg[m * 128 + e], acc[m]);
    }

#pragma unroll
    for (int j = 0; j < 8; j++) q[j] = qn[j];
  }

  float* op = out + ((size_t)b * NCOUT + m0) * NHW + n;
#pragma unroll
  for (int m = 0; m < 128; m++) {
    const int oc = m0 + m;
    const float sc = gamma[oc] * __builtin_amdgcn_rsqf(var[oc] + 1e-5f);
    const float bi = fmaf(-mean[oc], sc, beta[oc]);
    op[(size_t)m * NHW] = fmaf(acc[m], sc, bi);
  }
}

// ---------------------------------------------------------------------------
extern "C" void kernel_launch(void* const* d_in, const int* in_sizes, int n_in,
                              void* d_out, int out_size, void* d_ws, size_t ws_size,
                              hipStream_t stream) {
  const float* x     = (const float*)d_in[0];
  const float* Wq    = (const float*)d_in[1];
  const float* Wp    = (const float*)d_in[2];
  const float* Wd    = (const float*)d_in[3];
  const float* Wf    = (const float*)d_in[4];
  const float* gamma = (const float*)d_in[5];
  const float* beta  = (const float*)d_in[6];
  const float* mean  = (const float*)d_in[7];
  const float* var   = (const float*)d_in[8];
  float* out = (float*)d_out;

  char* ws = (char*)d_ws;
  float* qkv = (float*)ws;                                   // 8*192*16384*4 = 96 MiB
  float* dq  = (float*)(ws + (size_t)100663296);             // 8*64*16384*4  = 32 MiB
  float* kvb = (float*)(ws + (size_t)134217728);             // 8*16*72*4     = 36 KiB

  hipMemsetAsync(kvb, 0, (size_t)NB * 16 * 72 * sizeof(float), stream);

  k1_qkv<<<dim3(512, 2), 256, 0, stream>>>(x, Wq, qkv);
  k2_qkv_kv<<<dim3(64, 8), 256, 0, stream>>>(qkv, kvb);
  k2_dw<<<dim3(256, 8), 256, 0, stream>>>(qkv, Wp, Wd, dq, kvb);
  k3_attn_ffn<<<dim3(512, 2), 256, 0, stream>>>(qkv, dq, kvb, Wf, gamma, beta,
                                                mean, var, out);
}

// Round 2
// 1036.720 us; speedup vs baseline: 1.0610x; 1.0610x over previous
//
#include <hip/hip_runtime.h>

#define NB    8
#define NCIN  256
#define NH    128
#define NW    128
#define NHW   16384      // NH*NW
#define NQKV  192        // 3*T
#define NCOUT 256

// ---------------------------------------------------------------------------
// K1: qkv[b][m][n] = sum_k Wq[m][k] * x[b][k][n]   (1x1 conv as panel GEMM)
// M-tile 64 (grid.y=3), 4 waves/EU: 64 acc + ~25 addressing VGPRs, no spill.
// ---------------------------------------------------------------------------
__global__ __launch_bounds__(256, 4) void k1_qkv(
    const float* __restrict__ x, const float* __restrict__ Wq,
    float* __restrict__ qkv)
{
  const int tid = threadIdx.x;
  const int P0  = blockIdx.x * 256;
  const int b   = P0 >> 14;            // /NHW
  const int n0  = P0 & (NHW - 1);
  const int m0  = blockIdx.y * 64;

  const float* xp = x + (size_t)b * NCIN * NHW + n0 + tid;

  float acc[64];
#pragma unroll
  for (int m = 0; m < 64; m++) acc[m] = 0.f;

  float cur[4], nxt[4] = {0.f, 0.f, 0.f, 0.f};
#pragma unroll
  for (int j = 0; j < 4; j++) cur[j] = xp[(size_t)j * NHW];

  for (int k = 0; k < 256; k += 4) {
    if (k + 4 < 256) {
#pragma unroll
      for (int j = 0; j < 4; j++) nxt[j] = xp[(size_t)(k + 4 + j) * NHW];
    }
    const float* wr = Wq + (size_t)m0 * 256 + k;
#pragma unroll
    for (int m = 0; m < 64; m++) {
      acc[m] = fmaf(cur[0], wr[m * 256 + 0], acc[m]);
      acc[m] = fmaf(cur[1], wr[m * 256 + 1], acc[m]);
      acc[m] = fmaf(cur[2], wr[m * 256 + 2], acc[m]);
      acc[m] = fmaf(cur[3], wr[m * 256 + 3], acc[m]);
    }
#pragma unroll
    for (int j = 0; j < 4; j++) cur[j] = nxt[j];
  }

  float* op = qkv + (size_t)b * NQKV * NHW + (size_t)m0 * NHW + n0 + tid;
#pragma unroll
  for (int m = 0; m < 64; m++) op[(size_t)m * NHW] = acc[m];
}

// ---------------------------------------------------------------------------
// K2q: kv partial sums for attention groups 0..7 (sourced from qkv).
// kv[b][g][d][e] += sum_n relu(k)[d] * {v[e], 1}
// ---------------------------------------------------------------------------
__global__ __launch_bounds__(256, 4) void k2_qkv_kv(
    const float* __restrict__ qkv, float* __restrict__ kvb)
{
  __shared__ float red[4 * 72];
  const int tid = threadIdx.x;
  const int gg  = blockIdx.y;               // 0..7
  const int P0  = blockIdx.x * 2048;
  const int b   = P0 >> 14;
  const int n0  = P0 & (NHW - 1);

  const float* base = qkv + ((size_t)b * NQKV + gg * 24) * NHW + n0 + tid;

  float acc[72];
#pragma unroll
  for (int i = 0; i < 72; i++) acc[i] = 0.f;

  for (int it = 0; it < 8; it++) {
    const int off = it * 256;
    float kk[8], vv[8];
#pragma unroll
    for (int j = 0; j < 8; j++) kk[j] = fmaxf(base[(size_t)(8 + j) * NHW + off], 0.f);
#pragma unroll
    for (int j = 0; j < 8; j++) vv[j] = base[(size_t)(16 + j) * NHW + off];
#pragma unroll
    for (int d = 0; d < 8; d++) {
#pragma unroll
      for (int e = 0; e < 8; e++) acc[d * 9 + e] = fmaf(kk[d], vv[e], acc[d * 9 + e]);
      acc[d * 9 + 8] += kk[d];
    }
  }

  const int wave = tid >> 6, lane = tid & 63;
#pragma unroll
  for (int i = 0; i < 72; i++) {
    float v = acc[i];
    v += __shfl_down(v, 32);
    v += __shfl_down(v, 16);
    v += __shfl_down(v, 8);
    v += __shfl_down(v, 4);
    v += __shfl_down(v, 2);
    v += __shfl_down(v, 1);
    if (lane == 0) red[wave * 72 + i] = v;
  }
  __syncthreads();
  if (tid < 72) {
    float s = red[tid] + red[72 + tid] + red[144 + tid] + red[216 + tid];
    atomicAdd(&kvb[((size_t)b * 16 + gg) * 72 + tid], s);
  }
}

// ---------------------------------------------------------------------------
// K2d: for attention groups 8..15 (sourced from depthwise conv d):
//  - stage qkv halo (24 ch) in LDS, apply W_p in place -> p
//  - depthwise 3x3 -> d; write relu'd q-channels to dq; accumulate kv partials
// tile = 32 wide x 16 tall, halo 34x18
// ---------------------------------------------------------------------------
#define HALO_W 34
#define HALO_H 18
#define NPOS   (HALO_W * HALO_H)   // 612

__global__ __launch_bounds__(256, 2) void k2_dw(
    const float* __restrict__ qkv, const float* __restrict__ Wp,
    const float* __restrict__ Wd, float* __restrict__ dq,
    float* __restrict__ kvb)
{
  __shared__ float pbuf[24 * NPOS];
  __shared__ float red[4 * 72];

  const int tid  = threadIdx.x;
  const int gg8  = blockIdx.y;            // 0..7  (attention group = 8+gg8)
  const int bt   = blockIdx.x;            // b*32 + tile
  const int b    = bt >> 5;
  const int tile = bt & 31;
  const int ty0  = (tile >> 2) * 16;      // 8 tiles in y
  const int tx0  = (tile & 3) * 32;       // 4 tiles in x

  const float* src = qkv + ((size_t)b * NQKV + gg8 * 24) * NHW;

  // phase 1: load qkv halo into LDS (zero-padded)
  for (int idx = tid; idx < 24 * NPOS; idx += 256) {
    const int c = idx / NPOS, pos = idx % NPOS;
    const int hy = pos / HALO_W, hx = pos % HALO_W;
    const int y = ty0 + hy - 1, xx = tx0 + hx - 1;
    float v = 0.f;
    if (y >= 0 && y < NH && xx >= 0 && xx < NW) v = src[(size_t)c * NHW + y * NW + xx];
    pbuf[idx] = v;
  }
  __syncthreads();

  // phase 1b: apply W_p in place (each task owns its 8 LDS slots)
  for (int t = tid; t < 3 * NPOS; t += 256) {
    const int gloc = t / NPOS, pos = t % NPOS;
    float qv[8];
#pragma unroll
    for (int i = 0; i < 8; i++) qv[i] = pbuf[(gloc * 8 + i) * NPOS + pos];
    const float* wp = Wp + (size_t)(gg8 * 3 + gloc) * 64;
#pragma unroll
    for (int o = 0; o < 8; o++) {
      float s = 0.f;
#pragma unroll
      for (int i = 0; i < 8; i++) s = fmaf(wp[o * 8 + i], qv[i], s);
      pbuf[(gloc * 8 + o) * NPOS + pos] = s;
    }
  }
  __syncthreads();

  // phase 2: depthwise 3x3 + outputs
  float acc[72];
#pragma unroll
  for (int i = 0; i < 72; i++) acc[i] = 0.f;

  const float* wdb = Wd + (size_t)gg8 * 24 * 9;

  for (int pp = tid; pp < 512; pp += 256) {
    const int ty = pp >> 5, tx = pp & 31;
    const int n  = (ty0 + ty) * NW + (tx0 + tx);
    float kk[8], vv[8];
#pragma unroll
    for (int cc = 0; cc < 24; cc++) {
      const float* pb = pbuf + cc * NPOS + ty * HALO_W + tx;
      const float* w  = wdb + cc * 9;
      float s = 0.f;
      s = fmaf(w[0], pb[0], s);
      s = fmaf(w[1], pb[1], s);
      s = fmaf(w[2], pb[2], s);
      s = fmaf(w[3], pb[HALO_W + 0], s);
      s = fmaf(w[4], pb[HALO_W + 1], s);
      s = fmaf(w[5], pb[HALO_W + 2], s);
      s = fmaf(w[6], pb[2 * HALO_W + 0], s);
      s = fmaf(w[7], pb[2 * HALO_W + 1], s);
      s = fmaf(w[8], pb[2 * HALO_W + 2], s);
      if (cc < 8) {
        dq[((size_t)b * 64 + gg8 * 8 + cc) * NHW + n] = fmaxf(s, 0.f);
      } else if (cc < 16) {
        kk[cc - 8] = fmaxf(s, 0.f);
      } else {
        vv[cc - 16] = s;
      }
    }
#pragma unroll
    for (int d = 0; d < 8; d++) {
#pragma unroll
      for (int e = 0; e < 8; e++) acc[d * 9 + e] = fmaf(kk[d], vv[e], acc[d * 9 + e]);
      acc[d * 9 + 8] += kk[d];
    }
  }

  const int wave = tid >> 6, lane = tid & 63;
#pragma unroll
  for (int i = 0; i < 72; i++) {
    float v = acc[i];
    v += __shfl_down(v, 32);
    v += __shfl_down(v, 16);
    v += __shfl_down(v, 8);
    v += __shfl_down(v, 4);
    v += __shfl_down(v, 2);
    v += __shfl_down(v, 1);
    if (lane == 0) red[wave * 72 + i] = v;
  }
  __syncthreads();
  if (tid < 72) {
    float s = red[tid] + red[72 + tid] + red[144 + tid] + red[216 + tid];
    atomicAdd(&kvb[((size_t)b * 16 + (8 + gg8)) * 72 + tid], s);
  }
}

// ---------------------------------------------------------------------------
// K3: per pixel: q (16 groups x 8) -> o = (q . kv)[:8] / (q . kv)[8]
//     then y = Wffn @ o, BN affine.  M-tile 64 (grid.y=4), 4 waves/EU.
// ---------------------------------------------------------------------------
__global__ __launch_bounds__(256, 4) void k3_attn_ffn(
    const float* __restrict__ qkv, const float* __restrict__ dq,
    const float* __restrict__ kvb, const float* __restrict__ Wf,
    const float* __restrict__ gamma, const float* __restrict__ beta,
    const float* __restrict__ mean, const float* __restrict__ var,
    float* __restrict__ out)
{
  const int tid = threadIdx.x;
  const int P0  = blockIdx.x * 256;
  const int b   = P0 >> 14;
  const int n0  = P0 & (NHW - 1);
  const int m0  = blockIdx.y * 64;
  const int n   = n0 + tid;

  float acc[64];
#pragma unroll
  for (int m = 0; m < 64; m++) acc[m] = 0.f;

  const float* kvB = kvb + (size_t)b * 16 * 72;

  // prefetch q for group 0
  float q[8], qn[8];
  {
    const float* qp = qkv + ((size_t)b * NQKV + 0) * NHW + n;
#pragma unroll
    for (int j = 0; j < 8; j++) q[j] = qp[(size_t)j * NHW];
  }

  for (int g = 0; g < 16; g++) {
    // prefetch next group's q (raw)
    if (g < 15) {
      const int gn = g + 1;
      const float* qp = (gn < 8)
          ? qkv + ((size_t)b * NQKV + gn * 24) * NHW + n
          : dq + ((size_t)b * 64 + (gn - 8) * 8) * NHW + n;
#pragma unroll
      for (int j = 0; j < 8; j++) qn[j] = qp[(size_t)j * NHW];
    }

    float qv[8];
#pragma unroll
    for (int j = 0; j < 8; j++) qv[j] = (g < 8) ? fmaxf(q[j], 0.f) : q[j];

    const float* kvg = kvB + g * 72;
    float num[9];
#pragma unroll
    for (int e = 0; e < 9; e++) {
      float s = 0.f;
#pragma unroll
      for (int d = 0; d < 8; d++) s = fmaf(qv[d], kvg[d * 9 + e], s);
      num[e] = s;
    }
    const float r = __builtin_amdgcn_rcpf(num[8] + 1e-15f);
    float o8[8];
#pragma unroll
    for (int e = 0; e < 8; e++) o8[e] = num[e] * r;

    const float* wg = Wf + (size_t)m0 * 128 + g * 8;
#pragma unroll
    for (int m = 0; m < 64; m++) {
#pragma unroll
      for (int e = 0; e < 8; e++) acc[m] = fmaf(o8[e], wg[m * 128 + e], acc[m]);
    }

#pragma unroll
    for (int j = 0; j < 8; j++) q[j] = qn[j];
  }

  float* op = out + ((size_t)b * NCOUT + m0) * NHW + n;
#pragma unroll
  for (int m = 0; m < 64; m++) {
    const int oc = m0 + m;
    const float sc = gamma[oc] * __builtin_amdgcn_rsqf(var[oc] + 1e-5f);
    const float bi = fmaf(-mean[oc], sc, beta[oc]);
    op[(size_t)m * NHW] = fmaf(acc[m], sc, bi);
  }
}

// ---------------------------------------------------------------------------
extern "C" void kernel_launch(void* const* d_in, const int* in_sizes, int n_in,
                              void* d_out, int out_size, void* d_ws, size_t ws_size,
                              hipStream_t stream) {
  const float* x     = (const float*)d_in[0];
  const float* Wq    = (const float*)d_in[1];
  const float* Wp    = (const float*)d_in[2];
  const float* Wd    = (const float*)d_in[3];
  const float* Wf    = (const float*)d_in[4];
  const float* gamma = (const float*)d_in[5];
  const float* beta  = (const float*)d_in[6];
  const float* mean  = (const float*)d_in[7];
  const float* var   = (const float*)d_in[8];
  float* out = (float*)d_out;

  char* ws = (char*)d_ws;
  float* qkv = (float*)ws;                                   // 8*192*16384*4 = 96 MiB
  float* dq  = (float*)(ws + (size_t)100663296);             // 8*64*16384*4  = 32 MiB
  float* kvb = (float*)(ws + (size_t)134217728);             // 8*16*72*4     = 36 KiB

  hipMemsetAsync(kvb, 0, (size_t)NB * 16 * 72 * sizeof(float), stream);

  k1_qkv<<<dim3(512, 3), 256, 0, stream>>>(x, Wq, qkv);
  k2_qkv_kv<<<dim3(64, 8), 256, 0, stream>>>(qkv, kvb);
  k2_dw<<<dim3(256, 8), 256, 0, stream>>>(qkv, Wp, Wd, dq, kvb);
  k3_attn_ffn<<<dim3(512, 4), 256, 0, stream>>>(qkv, dq, kvb, Wf, gamma, beta,
                                                mean, var, out);
}